// Round 9
// baseline (232.925 us; speedup 1.0000x reference)
//
#include <hip/hip_runtime.h>

typedef __attribute__((ext_vector_type(4))) short short4v;
typedef __attribute__((ext_vector_type(8))) short short8v;
typedef __attribute__((ext_vector_type(2))) unsigned int uint2v;
typedef __attribute__((ext_vector_type(4))) unsigned int uint4v;
typedef __attribute__((ext_vector_type(4))) float f32x4;
typedef __attribute__((ext_vector_type(16))) float f32x16;

#define LSTRIDE 68                 // bf16 elems per LDS row (136 B; stride/8 odd -> conflict-free b64)
#define MATB (64 * LSTRIDE * 2)    // 8704 B per 64x64 bf16 matrix
#define TBUF (6 * MATB)            // 52224: one T buffer (Trh,Trl,Tih,Til,Tsh,Tsl)
#define LDSZ (2 * TBUF)            // 104448: ping-pong

// ws layout (pms_prep_k, proven rounds 6-8): [kslot 0..6][mat 0..5][qr][t][lane*16B]
// mat: 0=Cr_h 1=Cr_l 2=Ci_h 3=Ci_l 4=Cd_h 5=Cd_l   (Cd = Ci - Cr)
#define KSLOT_STRIDE 49152         // 6 mats * 8192
#define CS_OFF (7 * KSLOT_STRIDE)  // 344064: 2 mats (Cs1 h/l), Cs1 = C1r + C1i
#define KINIT_OFF (CS_OFF + 2 * 8192)  // 360448: 2 slots f32 (C0r, C0i-C0r)

__device__ __forceinline__ short bf16h(float v) {
    union { float f; unsigned u; } x; x.f = v;
    unsigned r = x.u + 0x7FFFu + ((x.u >> 16) & 1u);
    return (short)(r >> 16);
}
__device__ __forceinline__ float bf16tof(short s) {
    union { unsigned u; float f; } x; x.u = ((unsigned)(unsigned short)s) << 16;
    return x.f;
}
struct HL { unsigned h, l; };
__device__ __forceinline__ HL split2(float v0, float v1) {
    unsigned hp, lp;
    asm("v_cvt_pk_bf16_f32 %0, %1, %2" : "=v"(hp) : "v"(v0), "v"(v1));
    union { unsigned u; float f; } a, b;
    a.u = hp << 16;
    b.u = hp & 0xffff0000u;
    float l0 = v0 - a.f, l1 = v1 - b.f;
    asm("v_cvt_pk_bf16_f32 %0, %1, %2" : "=v"(lp) : "v"(l0), "v"(l1));
    HL r; r.h = hp; r.l = lp; return r;
}
__device__ __forceinline__ f32x16 MF(short8v a, short8v b, f32x16 c) {
    return __builtin_amdgcn_mfma_f32_32x32x16_bf16(a, b, c, 0, 0, 0);
}
__device__ __forceinline__ short8v negf(short8v a) {
    uint4v u = __builtin_bit_cast(uint4v, a);
    u ^= 0x80008000u;
    return __builtin_bit_cast(short8v, u);
}

// 6 coefficient fragments of one kslot/t (Ci pre-negated at load)
struct CF { short8v crh, crl, ncih, ncil, cdh, cdl; };
__device__ __forceinline__ CF loadCF(const char* cw, int qr, int lane, int t) {
    CF c;
    c.crh  =      *(const short8v*)(cw + ((size_t)(0 * 2 + qr) * 4 + t) * 1024 + lane * 16);
    c.crl  =      *(const short8v*)(cw + ((size_t)(1 * 2 + qr) * 4 + t) * 1024 + lane * 16);
    c.ncih = negf(*(const short8v*)(cw + ((size_t)(2 * 2 + qr) * 4 + t) * 1024 + lane * 16));
    c.ncil = negf(*(const short8v*)(cw + ((size_t)(3 * 2 + qr) * 4 + t) * 1024 + lane * 16));
    c.cdh  =      *(const short8v*)(cw + ((size_t)(4 * 2 + qr) * 4 + t) * 1024 + lane * 16);
    c.cdl  =      *(const short8v*)(cw + ((size_t)(5 * 2 + qr) * 4 + t) * 1024 + lane * 16);
    return c;
}

// ---------------- prep (unchanged, proven rounds 6-8) ----------------
__global__ void pms_prep_k(const float* __restrict__ coef, char* __restrict__ wsb) {
    const int blk = blockIdx.x;
    const int lane = threadIdx.x;
    const int lrow = lane & 31, lhi = lane >> 5;
    if (blk < 84) {
        const int s = blk / 12, rem = blk % 12;
        const int mat = rem >> 1, qr = rem & 1;
        const int which = mat >> 1, lo = mat & 1;   // which: 0=Cr 1=Ci 2=Cd
        const float* Pr = coef + (size_t)((s + 1) * 2 + 0) * 4096;
        const float* Pi = coef + (size_t)((s + 1) * 2 + 1) * 4096;
        for (int t = 0; t < 4; ++t) {
            short8v o;
            #pragma unroll
            for (int j = 0; j < 8; ++j) {
                int idx = (16 * t + 8 * lhi + j) * 64 + 32 * qr + lrow;
                float v = (which == 0) ? Pr[idx] : (which == 1) ? Pi[idx] : (Pi[idx] - Pr[idx]);
                short hh = bf16h(v);
                o[j] = lo ? bf16h(v - bf16tof(hh)) : hh;
            }
            *(short8v*)(wsb + (size_t)s * KSLOT_STRIDE + mat * 8192 + qr * 4096 + t * 1024 + lane * 16) = o;
        }
    } else if (blk < 88) {
        const int id = blk - 84;
        const int lo = id >> 1, qr = id & 1;        // Cs1 = C1r + C1i
        const float* Pr = coef + (size_t)(1 * 2 + 0) * 4096;
        const float* Pi = coef + (size_t)(1 * 2 + 1) * 4096;
        for (int t = 0; t < 4; ++t) {
            short8v o;
            #pragma unroll
            for (int j = 0; j < 8; ++j) {
                int idx = (16 * t + 8 * lhi + j) * 64 + 32 * qr + lrow;
                float v = Pr[idx] + Pi[idx];
                short hh = bf16h(v);
                o[j] = lo ? bf16h(v - bf16tof(hh)) : hh;
            }
            *(short8v*)(wsb + CS_OFF + lo * 8192 + qr * 4096 + t * 1024 + lane * 16) = o;
        }
    } else {
        const int id = blk - 88;                    // [slot][qr][qc]
        const int qc = id & 1, qr = (id >> 1) & 1, slot = id >> 2;
        float* dst = (float*)(wsb + KINIT_OFF + (size_t)(((slot * 2 + qr) * 2 + qc) * 64 + lane) * 64);
        #pragma unroll
        for (int v = 0; v < 16; ++v) {
            int r = 32 * qr + (v & 3) + 8 * (v >> 2) + 4 * lhi;
            int c = 32 * qc + lrow;
            float c0r = coef[c * 64 + r];
            float c0i = coef[4096 + c * 64 + r];
            dst[v] = (slot == 0) ? c0r : (c0i - c0r);
        }
    }
}

// ---------------- main: 512 threads, waves 0-3 chain / 4-7 coeff ----------------
__global__ __launch_bounds__(512, 2) void pms_main_k(
    const float* __restrict__ x, const char* __restrict__ wsb,
    float* __restrict__ out)
{
    extern __shared__ char smem[];
    const int tid  = threadIdx.x;
    const int lane = tid & 63;
    const int w    = tid >> 6;          // 0..7
    const int role = w >> 2;            // 0 = chain, 1 = coeff
    const int q    = w & 3;
    const int qr = q >> 1, qc = q & 1;
    const int lrow = lane & 31, lhi = lane >> 5;
    const size_t b = blockIdx.x;
    const float* xb = x + b * 8192;

    // ---- stage X -> buffer A mats 0..3 (T_1 = X); all 512 threads, 16 f32 each ----
    #pragma unroll
    for (int s = 0; s < 4; ++s) {
        int f = s * 2048 + tid * 4;          // 0..8191
        int p = f >> 12, m = (f >> 6) & 63, c = f & 63;
        f32x4 v = *(const f32x4*)(xb + f);
        HL a01 = split2(v[0], v[1]);
        HL a23 = split2(v[2], v[3]);
        int off = (m * LSTRIDE + c) * 2;
        uint2v u;
        u[0] = a01.h; u[1] = a23.h; *(uint2v*)(smem + (p * 2 + 0) * MATB + off) = u;
        u[0] = a01.l; u[1] = a23.l; *(uint2v*)(smem + (p * 2 + 1) * MATB + off) = u;
    }
    __syncthreads();

    // B-fragment from T buffer at byte offset `base`
    auto ldB = [&](int base, int mat, int t) -> short8v {
        const short4v* p = (const short4v*)(smem + base + mat * MATB
                             + (32 * qc + lrow) * (LSTRIDE * 2) + 32 * t + 16 * lhi);
        short4v a = p[0], c4 = p[1];
        short8v r;
        #pragma unroll
        for (int j = 0; j < 4; ++j) { r[j] = a[j]; r[j + 4] = c4[j]; }
        return r;
    };

    // ---- role state ----
    short8v xa[2][2][4];     // chain only: Xr^T, Xi^T h/l
    f32x16 accRr, accQ;      // coeff only
    if (role == 0) {
        #pragma unroll
        for (int pi = 0; pi < 2; ++pi)
        #pragma unroll
        for (int hl = 0; hl < 2; ++hl)
        #pragma unroll
        for (int t = 0; t < 4; ++t) {
            const short* mp = (const short*)(smem + (pi * 2 + hl) * MATB);
            short8v a;
            #pragma unroll
            for (int j = 0; j < 8; ++j)
                a[j] = mp[(16 * t + 8 * lhi + j) * LSTRIDE + 32 * qr + lrow];
            xa[pi][hl][t] = a;
        }
    } else {
        const f32x4* p0 = (const f32x4*)(wsb + KINIT_OFF + (size_t)(((0 + qr) * 2 + qc) * 64 + lane) * 64);
        #pragma unroll
        for (int g = 0; g < 4; ++g) {
            f32x4 a = p0[g];
            #pragma unroll
            for (int j = 0; j < 4; ++j) { accRr[4 * g + j] = a[j]; accQ[4 * g + j] = 0.f; }
        }
    }

    int cur = 0, nxt = TBUF;

    // ---- k = 2..7: coeff applies C_{k-1} to T_{k-1}; chain computes T_k -> nxt ----
    for (int k = 2; k <= 7; ++k) {
        const char* cw = wsb + (size_t)(k - 2) * KSLOT_STRIDE;

        if (role == 0) {
            // ===== chain: T_k = X * T_{k-1}, 12 MFMAs/t, fold -> nxt (incl Ts) =====
            f32x16 aTr, aTi;
            #pragma unroll
            for (int j = 0; j < 16; ++j) { aTr[j] = 0.f; aTi[j] = 0.f; }
            short8v Brh = ldB(cur, 0, 0), Brl = ldB(cur, 1, 0);
            short8v Bih = ldB(cur, 2, 0), Bil = ldB(cur, 3, 0);
            #pragma unroll
            for (int t = 0; t < 4; ++t) {
                short8v Nrh, Nrl, Nih, Nil;
                if (t < 3) {
                    Nrh = ldB(cur, 0, t + 1); Nrl = ldB(cur, 1, t + 1);
                    Nih = ldB(cur, 2, t + 1); Nil = ldB(cur, 3, t + 1);
                }
                short8v nBih = negf(Bih), nBil = negf(Bil);

                __builtin_amdgcn_s_setprio(1);
                aTr = MF(xa[0][0][t], Brh, aTr);
                aTi = MF(xa[1][0][t], Brh, aTi);
                aTr = MF(xa[0][0][t], Brl, aTr);
                aTi = MF(xa[1][0][t], Brl, aTi);
                aTr = MF(xa[0][1][t], Brh, aTr);
                aTi = MF(xa[1][1][t], Brh, aTi);
                aTr = MF(xa[1][0][t], nBih, aTr);
                aTi = MF(xa[0][0][t], Bih, aTi);
                aTr = MF(xa[1][0][t], nBil, aTr);
                aTi = MF(xa[0][0][t], Bil, aTi);
                aTr = MF(xa[1][1][t], nBih, aTr);
                aTi = MF(xa[0][1][t], Bih, aTi);
                __builtin_amdgcn_s_setprio(0);

                if (t < 3) { Brh = Nrh; Brl = Nrl; Bih = Nih; Bil = Nil; }
            }
            // fold: write Tr/Ti/Ts (h/l) into nxt
            {
                const int c = 32 * qc + lrow;
                #pragma unroll
                for (int g = 0; g < 4; ++g) {
                    int rbse = 32 * qr + 8 * g + 4 * lhi;
                    int off = (c * LSTRIDE + rbse) * 2;
                    float s0 = aTr[4 * g + 0] + aTi[4 * g + 0];
                    float s1 = aTr[4 * g + 1] + aTi[4 * g + 1];
                    float s2 = aTr[4 * g + 2] + aTi[4 * g + 2];
                    float s3 = aTr[4 * g + 3] + aTi[4 * g + 3];
                    HL a01 = split2(aTr[4 * g + 0], aTr[4 * g + 1]);
                    HL a23 = split2(aTr[4 * g + 2], aTr[4 * g + 3]);
                    HL b01 = split2(aTi[4 * g + 0], aTi[4 * g + 1]);
                    HL b23 = split2(aTi[4 * g + 2], aTi[4 * g + 3]);
                    HL c01 = split2(s0, s1);
                    HL c23 = split2(s2, s3);
                    uint2v u;
                    u[0] = a01.h; u[1] = a23.h; *(uint2v*)(smem + nxt + 0 * MATB + off) = u;
                    u[0] = a01.l; u[1] = a23.l; *(uint2v*)(smem + nxt + 1 * MATB + off) = u;
                    u[0] = b01.h; u[1] = b23.h; *(uint2v*)(smem + nxt + 2 * MATB + off) = u;
                    u[0] = b01.l; u[1] = b23.l; *(uint2v*)(smem + nxt + 3 * MATB + off) = u;
                    u[0] = c01.h; u[1] = c23.h; *(uint2v*)(smem + nxt + 4 * MATB + off) = u;
                    u[0] = c01.l; u[1] = c23.l; *(uint2v*)(smem + nxt + 5 * MATB + off) = u;
                }
            }
        } else if (k == 2) {
            // ===== coeff, quirk k=1 term: accRr += Cr*Tr - Ci*Ti ; accQ += Cd*Tr + Cs*Ti =====
            CF c0 = loadCF(cw, qr, lane, 0);
            short8v Brh = ldB(cur, 0, 0), Brl = ldB(cur, 1, 0);
            short8v Bih = ldB(cur, 2, 0), Bil = ldB(cur, 3, 0);
            #pragma unroll
            for (int t = 0; t < 4; ++t) {
                CF c1; short8v Nrh, Nrl, Nih, Nil;
                if (t < 3) {
                    c1 = loadCF(cw, qr, lane, t + 1);
                    Nrh = ldB(cur, 0, t + 1); Nrl = ldB(cur, 1, t + 1);
                    Nih = ldB(cur, 2, t + 1); Nil = ldB(cur, 3, t + 1);
                }
                short8v csh = *(const short8v*)(wsb + CS_OFF + ((size_t)(0 * 2 + qr) * 4 + t) * 1024 + lane * 16);
                short8v csl = *(const short8v*)(wsb + CS_OFF + ((size_t)(1 * 2 + qr) * 4 + t) * 1024 + lane * 16);

                __builtin_amdgcn_s_setprio(1);
                accRr = MF(c0.crh, Brh, accRr);
                accQ  = MF(c0.cdh, Brh, accQ);
                accRr = MF(c0.crh, Brl, accRr);
                accQ  = MF(c0.cdh, Brl, accQ);
                accRr = MF(c0.crl, Brh, accRr);
                accQ  = MF(c0.cdl, Brh, accQ);
                accRr = MF(c0.ncih, Bih, accRr);
                accQ  = MF(csh, Bih, accQ);
                accRr = MF(c0.ncih, Bil, accRr);
                accQ  = MF(csh, Bil, accQ);
                accRr = MF(c0.ncil, Bih, accRr);
                accQ  = MF(csl, Bih, accQ);
                __builtin_amdgcn_s_setprio(0);

                if (t < 3) { c0 = c1; Brh = Nrh; Brl = Nrl; Bih = Nih; Bil = Nil; }
            }
        } else {
            // ===== coeff, k>=3: accRr += Cr*Tr - Ci*Ti ; accQ += Cd*Ts (9 MFMAs/t) =====
            CF c0 = loadCF(cw, qr, lane, 0);
            short8v Brh = ldB(cur, 0, 0), Brl = ldB(cur, 1, 0);
            short8v Bih = ldB(cur, 2, 0), Bil = ldB(cur, 3, 0);
            short8v Bsh = ldB(cur, 4, 0), Bsl = ldB(cur, 5, 0);
            #pragma unroll
            for (int t = 0; t < 4; ++t) {
                CF c1; short8v Nrh, Nrl, Nih, Nil, Nsh, Nsl;
                if (t < 3) {
                    c1 = loadCF(cw, qr, lane, t + 1);
                    Nrh = ldB(cur, 0, t + 1); Nrl = ldB(cur, 1, t + 1);
                    Nih = ldB(cur, 2, t + 1); Nil = ldB(cur, 3, t + 1);
                    Nsh = ldB(cur, 4, t + 1); Nsl = ldB(cur, 5, t + 1);
                }

                __builtin_amdgcn_s_setprio(1);
                accRr = MF(c0.crh, Brh, accRr);
                accQ  = MF(c0.cdh, Bsh, accQ);
                accRr = MF(c0.crh, Brl, accRr);
                accQ  = MF(c0.cdh, Bsl, accQ);
                accRr = MF(c0.crl, Brh, accRr);
                accQ  = MF(c0.cdl, Bsh, accQ);
                accRr = MF(c0.ncih, Bih, accRr);
                accRr = MF(c0.ncih, Bil, accRr);
                accRr = MF(c0.ncil, Bih, accRr);
                __builtin_amdgcn_s_setprio(0);

                if (t < 3) {
                    c0 = c1; Brh = Nrh; Brl = Nrl; Bih = Nih; Bil = Nil;
                    Bsh = Nsh; Bsl = Nsl;
                }
            }
        }

        __syncthreads();   // T_k visible; everyone done reading T_{k-1}
        int tmp = cur; cur = nxt; nxt = tmp;
    }

    // ---- final: coeff applies C7 (kslot 6) to T7 in cur ----
    if (role == 1) {
        const char* cw = wsb + (size_t)6 * KSLOT_STRIDE;
        CF c0 = loadCF(cw, qr, lane, 0);
        short8v Brh = ldB(cur, 0, 0), Brl = ldB(cur, 1, 0);
        short8v Bih = ldB(cur, 2, 0), Bil = ldB(cur, 3, 0);
        short8v Bsh = ldB(cur, 4, 0), Bsl = ldB(cur, 5, 0);
        #pragma unroll
        for (int t = 0; t < 4; ++t) {
            CF c1; short8v Nrh, Nrl, Nih, Nil, Nsh, Nsl;
            if (t < 3) {
                c1 = loadCF(cw, qr, lane, t + 1);
                Nrh = ldB(cur, 0, t + 1); Nrl = ldB(cur, 1, t + 1);
                Nih = ldB(cur, 2, t + 1); Nil = ldB(cur, 3, t + 1);
                Nsh = ldB(cur, 4, t + 1); Nsl = ldB(cur, 5, t + 1);
            }

            __builtin_amdgcn_s_setprio(1);
            accRr = MF(c0.crh, Brh, accRr);
            accQ  = MF(c0.cdh, Bsh, accQ);
            accRr = MF(c0.crh, Brl, accRr);
            accQ  = MF(c0.cdh, Bsl, accQ);
            accRr = MF(c0.crl, Brh, accRr);
            accQ  = MF(c0.cdl, Bsh, accQ);
            accRr = MF(c0.ncih, Bih, accRr);
            accRr = MF(c0.ncih, Bil, accRr);
            accRr = MF(c0.ncil, Bih, accRr);
            __builtin_amdgcn_s_setprio(0);

            if (t < 3) {
                c0 = c1; Brh = Nrh; Brl = Nrl; Bih = Nih; Bil = Nil;
                Bsh = Nsh; Bsl = Nsl;
            }
        }
    }

    __syncthreads();   // coeff done reading T7; T buffers dead

    // ---- epilogue: coeff waves write f32 result (transposed) to LDS staging ----
    if (role == 1) {
        const f32x4* p1 = (const f32x4*)(wsb + KINIT_OFF + (size_t)(((2 + qr) * 2 + qc) * 64 + lane) * 64);
        const int c = 32 * qc + lrow;
        #pragma unroll
        for (int g = 0; g < 4; ++g) {
            f32x4 d = p1[g];
            int rbse = 32 * qr + 8 * g + 4 * lhi;
            f32x4 vr, vi;
            #pragma unroll
            for (int j = 0; j < 4; ++j) {
                float rr = accRr[4 * g + j];
                vr[j] = rr;
                vi[j] = rr + accQ[4 * g + j] + d[j];
            }
            *(f32x4*)(smem + (size_t)(0 * 4352 + c * LSTRIDE + rbse) * 4) = vr;
            *(f32x4*)(smem + (size_t)(1 * 4352 + c * LSTRIDE + rbse) * 4) = vi;
        }
    }
    __syncthreads();

    // ---- coalesced store, all 512 threads ----
    float* ob = out + b * 8192;
    #pragma unroll
    for (int s = 0; s < 4; ++s) {
        int f = s * 2048 + tid * 4;
        int p = f >> 12, m = (f >> 6) & 63, n = f & 63;
        *(f32x4*)(ob + f) = *(const f32x4*)(smem + (size_t)(p * 4352 + m * LSTRIDE + n) * 4);
    }
}

extern "C" void kernel_launch(void* const* d_in, const int* in_sizes, int n_in,
                              void* d_out, int out_size, void* d_ws, size_t ws_size,
                              hipStream_t stream) {
    const float* x    = (const float*)d_in[0];
    const float* coef = (const float*)d_in[1];
    float* out = (float*)d_out;
    char*  wsb = (char*)d_ws;
    const int B = in_sizes[0] / 8192;   // 2048

    (void)hipFuncSetAttribute(reinterpret_cast<const void*>(&pms_main_k),
                              hipFuncAttributeMaxDynamicSharedMemorySize, LDSZ);

    pms_prep_k<<<96, 64, 0, stream>>>(coef, wsb);
    pms_main_k<<<B, 512, LDSZ, stream>>>(x, wsb, out);
}

// Round 10
// 158.385 us; speedup vs baseline: 1.4706x; 1.4706x over previous
//
#include <hip/hip_runtime.h>

typedef __attribute__((ext_vector_type(4))) short short4v;
typedef __attribute__((ext_vector_type(8))) short short8v;
typedef __attribute__((ext_vector_type(2))) unsigned int uint2v;
typedef __attribute__((ext_vector_type(4))) unsigned int uint4v;
typedef __attribute__((ext_vector_type(4))) float f32x4;
typedef __attribute__((ext_vector_type(16))) float f32x16;

#define LSTRIDE 68                 // bf16 elems per LDS row (136 B; conflict-free b64)
#define MATB (64 * LSTRIDE * 2)    // 8704 B per 64x64 bf16 matrix
#define TBUF (6 * MATB)            // 52224: one T buffer (Trh,Trl,Tih,Til,Tsh,Tsl)
#define FRAGOFF (2 * TBUF)         // 104448: A-frag region (6 mats x 8KB)
#define LDSZ (FRAGOFF + 6 * 8192)  // 153600 (needs hipFuncSetAttribute; < 160K)

// ws layout (pms_prep_k, proven rounds 6-9): [kslot 0..6][mat 0..5][qr][t][lane*16B]
// mat: 0=Cr_h 1=Cr_l 2=Ci_h 3=Ci_l 4=Cd_h 5=Cd_l   (Cd = Ci - Cr)
#define KSLOT_STRIDE 49152
#define CS_OFF (7 * KSLOT_STRIDE)      // 2 mats (Cs1 h/l), Cs1 = C1r + C1i
#define KINIT_OFF (CS_OFF + 2 * 8192)  // 2 slots f32 (C0r, C0i-C0r)

__device__ __forceinline__ short bf16h(float v) {
    union { float f; unsigned u; } x; x.f = v;
    unsigned r = x.u + 0x7FFFu + ((x.u >> 16) & 1u);
    return (short)(r >> 16);
}
__device__ __forceinline__ float bf16tof(short s) {
    union { unsigned u; float f; } x; x.u = ((unsigned)(unsigned short)s) << 16;
    return x.f;
}
struct HL { unsigned h, l; };
__device__ __forceinline__ HL split2(float v0, float v1) {
    unsigned hp, lp;
    asm("v_cvt_pk_bf16_f32 %0, %1, %2" : "=v"(hp) : "v"(v0), "v"(v1));
    union { unsigned u; float f; } a, b;
    a.u = hp << 16;
    b.u = hp & 0xffff0000u;
    float l0 = v0 - a.f, l1 = v1 - b.f;
    asm("v_cvt_pk_bf16_f32 %0, %1, %2" : "=v"(lp) : "v"(l0), "v"(l1));
    HL r; r.h = hp; r.l = lp; return r;
}
__device__ __forceinline__ f32x16 MF(short8v a, short8v b, f32x16 c) {
    return __builtin_amdgcn_mfma_f32_32x32x16_bf16(a, b, c, 0, 0, 0);
}
__device__ __forceinline__ short8v negf(short8v a) {
    uint4v u = __builtin_bit_cast(uint4v, a);
    u ^= 0x80008000u;
    return __builtin_bit_cast(short8v, u);
}

struct CF { short8v crh, crl, ncih, ncil, cdh, cdl; };
__device__ __forceinline__ CF loadCF(const char* cw, int qr, int lane, int t) {
    CF c;
    c.crh  =      *(const short8v*)(cw + ((size_t)(0 * 2 + qr) * 4 + t) * 1024 + lane * 16);
    c.crl  =      *(const short8v*)(cw + ((size_t)(1 * 2 + qr) * 4 + t) * 1024 + lane * 16);
    c.ncih = negf(*(const short8v*)(cw + ((size_t)(2 * 2 + qr) * 4 + t) * 1024 + lane * 16));
    c.ncil = negf(*(const short8v*)(cw + ((size_t)(3 * 2 + qr) * 4 + t) * 1024 + lane * 16));
    c.cdh  =      *(const short8v*)(cw + ((size_t)(4 * 2 + qr) * 4 + t) * 1024 + lane * 16);
    c.cdl  =      *(const short8v*)(cw + ((size_t)(5 * 2 + qr) * 4 + t) * 1024 + lane * 16);
    return c;
}

// ---------------- prep (unchanged, proven rounds 6-9) ----------------
__global__ void pms_prep_k(const float* __restrict__ coef, char* __restrict__ wsb) {
    const int blk = blockIdx.x;
    const int lane = threadIdx.x;
    const int lrow = lane & 31, lhi = lane >> 5;
    if (blk < 84) {
        const int s = blk / 12, rem = blk % 12;
        const int mat = rem >> 1, qr = rem & 1;
        const int which = mat >> 1, lo = mat & 1;
        const float* Pr = coef + (size_t)((s + 1) * 2 + 0) * 4096;
        const float* Pi = coef + (size_t)((s + 1) * 2 + 1) * 4096;
        for (int t = 0; t < 4; ++t) {
            short8v o;
            #pragma unroll
            for (int j = 0; j < 8; ++j) {
                int idx = (16 * t + 8 * lhi + j) * 64 + 32 * qr + lrow;
                float v = (which == 0) ? Pr[idx] : (which == 1) ? Pi[idx] : (Pi[idx] - Pr[idx]);
                short hh = bf16h(v);
                o[j] = lo ? bf16h(v - bf16tof(hh)) : hh;
            }
            *(short8v*)(wsb + (size_t)s * KSLOT_STRIDE + mat * 8192 + qr * 4096 + t * 1024 + lane * 16) = o;
        }
    } else if (blk < 88) {
        const int id = blk - 84;
        const int lo = id >> 1, qr = id & 1;
        const float* Pr = coef + (size_t)(1 * 2 + 0) * 4096;
        const float* Pi = coef + (size_t)(1 * 2 + 1) * 4096;
        for (int t = 0; t < 4; ++t) {
            short8v o;
            #pragma unroll
            for (int j = 0; j < 8; ++j) {
                int idx = (16 * t + 8 * lhi + j) * 64 + 32 * qr + lrow;
                float v = Pr[idx] + Pi[idx];
                short hh = bf16h(v);
                o[j] = lo ? bf16h(v - bf16tof(hh)) : hh;
            }
            *(short8v*)(wsb + CS_OFF + lo * 8192 + qr * 4096 + t * 1024 + lane * 16) = o;
        }
    } else {
        const int id = blk - 88;
        const int qc = id & 1, qr = (id >> 1) & 1, slot = id >> 2;
        float* dst = (float*)(wsb + KINIT_OFF + (size_t)(((slot * 2 + qr) * 2 + qc) * 64 + lane) * 64);
        #pragma unroll
        for (int v = 0; v < 16; ++v) {
            int r = 32 * qr + (v & 3) + 8 * (v >> 2) + 4 * lhi;
            int c = 32 * qc + lrow;
            float c0r = coef[c * 64 + r];
            float c0i = coef[4096 + c * 64 + r];
            dst[v] = (slot == 0) ? c0r : (c0i - c0r);
        }
    }
}

// ---------------- main: 512 threads; waves 0-3 chain-K, 4-7 coeff-K ----------------
__global__ __launch_bounds__(512, 2) void pms_main_k(
    const float* __restrict__ x, const char* __restrict__ wsb,
    float* __restrict__ out)
{
    extern __shared__ char smem[];
    const int tid  = threadIdx.x;
    const int lane = tid & 63;
    const int w    = tid >> 6;          // 0..7
    const int role = w >> 2;            // 0 = chain, 1 = coeff
    const int q    = w & 3;
    const int qr = q >> 1, qc = q & 1;
    const int lrow = lane & 31, lhi = lane >> 5;
    const size_t b = blockIdx.x;
    const float* xb = x + b * 8192;

    // ---- stage X -> buf A mats 0..5 (Xr,Xi,Xs h/l); T_1 = X incl Ts_1 = Xs ----
    #pragma unroll
    for (int s = 0; s < 2; ++s) {
        int f = s * 2048 + tid * 4;          // [0, 4096)
        int m = f >> 6, c = f & 63;
        f32x4 vr = *(const f32x4*)(xb + f);
        f32x4 vi = *(const f32x4*)(xb + 4096 + f);
        f32x4 vs;
        #pragma unroll
        for (int j = 0; j < 4; ++j) vs[j] = vr[j] + vi[j];
        HL r01 = split2(vr[0], vr[1]), r23 = split2(vr[2], vr[3]);
        HL i01 = split2(vi[0], vi[1]), i23 = split2(vi[2], vi[3]);
        HL s01 = split2(vs[0], vs[1]), s23 = split2(vs[2], vs[3]);
        int off = (m * LSTRIDE + c) * 2;
        uint2v u;
        u[0] = r01.h; u[1] = r23.h; *(uint2v*)(smem + 0 * MATB + off) = u;
        u[0] = r01.l; u[1] = r23.l; *(uint2v*)(smem + 1 * MATB + off) = u;
        u[0] = i01.h; u[1] = i23.h; *(uint2v*)(smem + 2 * MATB + off) = u;
        u[0] = i01.l; u[1] = i23.l; *(uint2v*)(smem + 3 * MATB + off) = u;
        u[0] = s01.h; u[1] = s23.h; *(uint2v*)(smem + 4 * MATB + off) = u;
        u[0] = s01.l; u[1] = s23.l; *(uint2v*)(smem + 5 * MATB + off) = u;
    }
    __syncthreads();

    // ---- build A-frag region: 48 slots (6 mats x 2 qr x 4 t), 6 per wave ----
    #pragma unroll
    for (int j6 = 0; j6 < 6; ++j6) {
        int s = w * 6 + j6;                 // 0..47
        int mat = s >> 3, r = s & 7;
        int fqr = r >> 2, ft = r & 3;
        const short* mp = (const short*)(smem + mat * MATB);
        short8v a;
        #pragma unroll
        for (int j = 0; j < 8; ++j)
            a[j] = mp[(16 * ft + 8 * lhi + j) * LSTRIDE + 32 * fqr + lrow];
        *(short8v*)(smem + FRAGOFF + ((size_t)(mat * 2 + fqr) * 4 + ft) * 1024 + lane * 16) = a;
    }

    // coeff accumulators
    f32x16 accRr, accQ;
    if (role == 1) {
        const f32x4* p0 = (const f32x4*)(wsb + KINIT_OFF + (size_t)(((0 + qr) * 2 + qc) * 64 + lane) * 64);
        #pragma unroll
        for (int g = 0; g < 4; ++g) {
            f32x4 a = p0[g];
            #pragma unroll
            for (int j = 0; j < 4; ++j) { accRr[4 * g + j] = a[j]; accQ[4 * g + j] = 0.f; }
        }
    }
    __syncthreads();

    auto ldB = [&](int base, int mat, int t) -> short8v {
        const short4v* p = (const short4v*)(smem + base + mat * MATB
                             + (32 * qc + lrow) * (LSTRIDE * 2) + 32 * t + 16 * lhi);
        short4v a = p[0], c4 = p[1];
        short8v r;
        #pragma unroll
        for (int j = 0; j < 4; ++j) { r[j] = a[j]; r[j + 4] = c4[j]; }
        return r;
    };
    auto ldA = [&](int mat, int t) -> short8v {
        return *(const short8v*)(smem + FRAGOFF + ((size_t)(mat * 2 + qr) * 4 + t) * 1024 + lane * 16);
    };

    int cur = 0, nxt = TBUF;
    CF cnxt;
    if (role == 1) cnxt = loadCF(wsb, qr, lane, 0);   // kslot 0, t=0

    // ---- k = 2..7: coeff applies C_{k-1} to T_{k-1}; chain computes T_k -> nxt ----
    for (int k = 2; k <= 7; ++k) {
        if (role == 0) {
            // ===== chain-K: m1=Xr*Tr, m2=Xi*Ti, m3=Xs*Ts (9 MFMAs/t) =====
            f32x16 m1, m2, m3;
            #pragma unroll
            for (int j = 0; j < 16; ++j) { m1[j] = 0.f; m2[j] = 0.f; m3[j] = 0.f; }
            #pragma unroll
            for (int t = 0; t < 4; ++t) {
                short8v xrh = ldA(0, t), xrl = ldA(1, t);
                short8v xih = ldA(2, t), xil = ldA(3, t);
                short8v xsh = ldA(4, t), xsl = ldA(5, t);
                short8v Brh = ldB(cur, 0, t), Brl = ldB(cur, 1, t);
                short8v Bih = ldB(cur, 2, t), Bil = ldB(cur, 3, t);
                short8v Bsh = ldB(cur, 4, t), Bsl = ldB(cur, 5, t);

                __builtin_amdgcn_s_setprio(1);
                m1 = MF(xrh, Brh, m1);
                m2 = MF(xih, Bih, m2);
                m3 = MF(xsh, Bsh, m3);
                m1 = MF(xrh, Brl, m1);
                m2 = MF(xih, Bil, m2);
                m3 = MF(xsh, Bsl, m3);
                m1 = MF(xrl, Brh, m1);
                m2 = MF(xil, Bih, m2);
                m3 = MF(xsl, Bsh, m3);
                __builtin_amdgcn_s_setprio(0);
            }
            // fold: Tr = m1-m2; Ti = m3-m1-m2; Ts = Tr+Ti -> write 6 mats to nxt
            {
                const int c = 32 * qc + lrow;
                #pragma unroll
                for (int g = 0; g < 4; ++g) {
                    int rbse = 32 * qr + 8 * g + 4 * lhi;
                    int off = (c * LSTRIDE + rbse) * 2;
                    float tr0 = m1[4*g+0] - m2[4*g+0], tr1 = m1[4*g+1] - m2[4*g+1];
                    float tr2 = m1[4*g+2] - m2[4*g+2], tr3 = m1[4*g+3] - m2[4*g+3];
                    float ti0 = m3[4*g+0] - m1[4*g+0] - m2[4*g+0];
                    float ti1 = m3[4*g+1] - m1[4*g+1] - m2[4*g+1];
                    float ti2 = m3[4*g+2] - m1[4*g+2] - m2[4*g+2];
                    float ti3 = m3[4*g+3] - m1[4*g+3] - m2[4*g+3];
                    HL a01 = split2(tr0, tr1), a23 = split2(tr2, tr3);
                    HL b01 = split2(ti0, ti1), b23 = split2(ti2, ti3);
                    HL c01 = split2(tr0 + ti0, tr1 + ti1), c23 = split2(tr2 + ti2, tr3 + ti3);
                    uint2v u;
                    u[0] = a01.h; u[1] = a23.h; *(uint2v*)(smem + nxt + 0 * MATB + off) = u;
                    u[0] = a01.l; u[1] = a23.l; *(uint2v*)(smem + nxt + 1 * MATB + off) = u;
                    u[0] = b01.h; u[1] = b23.h; *(uint2v*)(smem + nxt + 2 * MATB + off) = u;
                    u[0] = b01.l; u[1] = b23.l; *(uint2v*)(smem + nxt + 3 * MATB + off) = u;
                    u[0] = c01.h; u[1] = c23.h; *(uint2v*)(smem + nxt + 4 * MATB + off) = u;
                    u[0] = c01.l; u[1] = c23.l; *(uint2v*)(smem + nxt + 5 * MATB + off) = u;
                }
            }
        } else if (k == 2) {
            // ===== coeff-K quirk (C1): accRr += Cr*Tr - Ci*Ti ; accQ += Cd*Tr + Cs*Ti =====
            const char* cw = wsb;   // kslot 0
            CF c0 = cnxt;
            #pragma unroll
            for (int t = 0; t < 4; ++t) {
                CF c1;
                if (t < 3) c1 = loadCF(cw, qr, lane, t + 1);
                short8v csh = *(const short8v*)(wsb + CS_OFF + ((size_t)(0 * 2 + qr) * 4 + t) * 1024 + lane * 16);
                short8v csl = *(const short8v*)(wsb + CS_OFF + ((size_t)(1 * 2 + qr) * 4 + t) * 1024 + lane * 16);
                short8v Brh = ldB(cur, 0, t), Brl = ldB(cur, 1, t);
                short8v Bih = ldB(cur, 2, t), Bil = ldB(cur, 3, t);

                __builtin_amdgcn_s_setprio(1);
                accRr = MF(c0.crh, Brh, accRr);
                accQ  = MF(c0.cdh, Brh, accQ);
                accRr = MF(c0.crh, Brl, accRr);
                accQ  = MF(c0.cdh, Brl, accQ);
                accRr = MF(c0.crl, Brh, accRr);
                accQ  = MF(c0.cdl, Brh, accQ);
                accRr = MF(c0.ncih, Bih, accRr);
                accQ  = MF(csh, Bih, accQ);
                accRr = MF(c0.ncih, Bil, accRr);
                accQ  = MF(csh, Bil, accQ);
                accRr = MF(c0.ncil, Bih, accRr);
                accQ  = MF(csl, Bih, accQ);
                __builtin_amdgcn_s_setprio(0);

                if (t < 3) c0 = c1;
            }
            cnxt = loadCF(wsb + (size_t)1 * KSLOT_STRIDE, qr, lane, 0);
        } else {
            // ===== coeff-K (k>=3): accRr += Cr*Tr - Ci*Ti ; accQ += Cd*Ts (9/t) =====
            const char* cw = wsb + (size_t)(k - 2) * KSLOT_STRIDE;
            CF c0 = cnxt;
            #pragma unroll
            for (int t = 0; t < 4; ++t) {
                CF c1;
                if (t < 3) c1 = loadCF(cw, qr, lane, t + 1);
                short8v Brh = ldB(cur, 0, t), Brl = ldB(cur, 1, t);
                short8v Bih = ldB(cur, 2, t), Bil = ldB(cur, 3, t);
                short8v Bsh = ldB(cur, 4, t), Bsl = ldB(cur, 5, t);

                __builtin_amdgcn_s_setprio(1);
                accRr = MF(c0.crh, Brh, accRr);
                accQ  = MF(c0.cdh, Bsh, accQ);
                accRr = MF(c0.crh, Brl, accRr);
                accQ  = MF(c0.cdh, Bsl, accQ);
                accRr = MF(c0.crl, Brh, accRr);
                accQ  = MF(c0.cdl, Bsh, accQ);
                accRr = MF(c0.ncih, Bih, accRr);
                accRr = MF(c0.ncih, Bil, accRr);
                accRr = MF(c0.ncil, Bih, accRr);
                __builtin_amdgcn_s_setprio(0);

                if (t < 3) c0 = c1;
            }
            cnxt = loadCF(wsb + (size_t)(k - 1) * KSLOT_STRIDE, qr, lane, 0);  // k=7 -> kslot 6
        }

        __syncthreads();   // T_k visible; all reads of T_{k-1} done
        int tmp = cur; cur = nxt; nxt = tmp;
    }

    // ---- final: coeff applies C7 (kslot 6) to T7 in cur ----
    if (role == 1) {
        const char* cw = wsb + (size_t)6 * KSLOT_STRIDE;
        CF c0 = cnxt;
        #pragma unroll
        for (int t = 0; t < 4; ++t) {
            CF c1;
            if (t < 3) c1 = loadCF(cw, qr, lane, t + 1);
            short8v Brh = ldB(cur, 0, t), Brl = ldB(cur, 1, t);
            short8v Bih = ldB(cur, 2, t), Bil = ldB(cur, 3, t);
            short8v Bsh = ldB(cur, 4, t), Bsl = ldB(cur, 5, t);

            __builtin_amdgcn_s_setprio(1);
            accRr = MF(c0.crh, Brh, accRr);
            accQ  = MF(c0.cdh, Bsh, accQ);
            accRr = MF(c0.crh, Brl, accRr);
            accQ  = MF(c0.cdh, Bsl, accQ);
            accRr = MF(c0.crl, Brh, accRr);
            accQ  = MF(c0.cdl, Bsh, accQ);
            accRr = MF(c0.ncih, Bih, accRr);
            accRr = MF(c0.ncih, Bil, accRr);
            accRr = MF(c0.ncil, Bih, accRr);
            __builtin_amdgcn_s_setprio(0);

            if (t < 3) c0 = c1;
        }
    }
    __syncthreads();   // coeff done reading T7; both T buffers dead

    // ---- epilogue: coeff waves stage f32 result (transposed) into nxt region ----
    if (role == 1) {
        const f32x4* p1 = (const f32x4*)(wsb + KINIT_OFF + (size_t)(((2 + qr) * 2 + qc) * 64 + lane) * 64);
        const int c = 32 * qc + lrow;
        #pragma unroll
        for (int g = 0; g < 4; ++g) {
            f32x4 d = p1[g];
            int rbse = 32 * qr + 8 * g + 4 * lhi;
            f32x4 vr, vi;
            #pragma unroll
            for (int j = 0; j < 4; ++j) {
                float rr = accRr[4 * g + j];
                vr[j] = rr;
                vi[j] = rr + accQ[4 * g + j] + d[j];
            }
            *(f32x4*)(smem + nxt + (size_t)(0 * 4352 + c * LSTRIDE + rbse) * 4) = vr;
            *(f32x4*)(smem + nxt + (size_t)(1 * 4352 + c * LSTRIDE + rbse) * 4) = vi;
        }
    }
    __syncthreads();

    // ---- coalesced store, all 512 threads ----
    float* ob = out + b * 8192;
    #pragma unroll
    for (int s = 0; s < 4; ++s) {
        int f = s * 2048 + tid * 4;
        int p = f >> 12, m = (f >> 6) & 63, n = f & 63;
        *(f32x4*)(ob + f) = *(const f32x4*)(smem + nxt + (size_t)(p * 4352 + m * LSTRIDE + n) * 4);
    }
}

extern "C" void kernel_launch(void* const* d_in, const int* in_sizes, int n_in,
                              void* d_out, int out_size, void* d_ws, size_t ws_size,
                              hipStream_t stream) {
    const float* x    = (const float*)d_in[0];
    const float* coef = (const float*)d_in[1];
    float* out = (float*)d_out;
    char*  wsb = (char*)d_ws;
    const int B = in_sizes[0] / 8192;   // 2048

    (void)hipFuncSetAttribute(reinterpret_cast<const void*>(&pms_main_k),
                              hipFuncAttributeMaxDynamicSharedMemorySize, LDSZ);

    pms_prep_k<<<96, 64, 0, stream>>>(coef, wsb);
    pms_main_k<<<B, 512, LDSZ, stream>>>(x, wsb, out);
}

// Round 12
// 152.007 us; speedup vs baseline: 1.5323x; 1.0420x over previous
//
#include <hip/hip_runtime.h>

typedef __attribute__((ext_vector_type(4))) short short4v;
typedef __attribute__((ext_vector_type(8))) short short8v;
typedef __attribute__((ext_vector_type(2))) unsigned int uint2v;
typedef __attribute__((ext_vector_type(4))) unsigned int uint4v;
typedef __attribute__((ext_vector_type(4))) float f32x4;
typedef __attribute__((ext_vector_type(16))) float f32x16;

#define LSTRIDE 68                 // bf16 elems per LDS row (136 B; conflict-free b64)
#define MATB (64 * LSTRIDE * 2)    // 8704 B per 64x64 bf16 matrix
#define TREG (6 * MATB)            // 52224: in-place T mats 0=Trh 1=Trl 2=Tih 3=Til 4=Tsh 5=Tsl
#define FRAG2OFF TREG              // Xi A-frags: [hl][qr][t] = 16 slots x 1KB
#define LDSZ (TREG + 16384)        // 68608 -> 2 blocks/CU (needs SetAttribute)

// ws layout (pms_prep_k, proven rounds 6-11): [kslot 0..6][mat 0..5][qr][t][lane*16B]
// mat: 0=Cr_h 1=Cr_l 2=Ci_h 3=Ci_l 4=Cd_h 5=Cd_l   (Cd = Ci - Cr)
#define KSLOT_STRIDE 49152
#define CS_OFF (7 * KSLOT_STRIDE)      // 2 mats (Cs1 h/l), Cs1 = C1r + C1i
#define KINIT_OFF (CS_OFF + 2 * 8192)  // 2 slots f32 (C0r, C0i-C0r)

__device__ __forceinline__ short bf16h(float v) {
    union { float f; unsigned u; } x; x.f = v;
    unsigned r = x.u + 0x7FFFu + ((x.u >> 16) & 1u);
    return (short)(r >> 16);
}
__device__ __forceinline__ float bf16tof(short s) {
    union { unsigned u; float f; } x; x.u = ((unsigned)(unsigned short)s) << 16;
    return x.f;
}
struct HL { unsigned h, l; };
__device__ __forceinline__ HL split2(float v0, float v1) {
    unsigned hp, lp;
    asm("v_cvt_pk_bf16_f32 %0, %1, %2" : "=v"(hp) : "v"(v0), "v"(v1));
    union { unsigned u; float f; } a, b;
    a.u = hp << 16;
    b.u = hp & 0xffff0000u;
    float l0 = v0 - a.f, l1 = v1 - b.f;
    asm("v_cvt_pk_bf16_f32 %0, %1, %2" : "=v"(lp) : "v"(l0), "v"(l1));
    HL r; r.h = hp; r.l = lp; return r;
}
__device__ __forceinline__ f32x16 MF(short8v a, short8v b, f32x16 c) {
    return __builtin_amdgcn_mfma_f32_32x32x16_bf16(a, b, c, 0, 0, 0);
}
__device__ __forceinline__ short8v negf(short8v a) {
    uint4v u = __builtin_bit_cast(uint4v, a);
    u ^= 0x80008000u;
    return __builtin_bit_cast(short8v, u);
}

// 6 coefficient fragments of one kslot/t (Ci pre-negated at load)
struct CF { short8v crh, crl, ncih, ncil, cdh, cdl; };
__device__ __forceinline__ CF loadCF(const char* cw, int qr, int lane, int t) {
    CF c;
    c.crh  =      *(const short8v*)(cw + ((size_t)(0 * 2 + qr) * 4 + t) * 1024 + lane * 16);
    c.crl  =      *(const short8v*)(cw + ((size_t)(1 * 2 + qr) * 4 + t) * 1024 + lane * 16);
    c.ncih = negf(*(const short8v*)(cw + ((size_t)(2 * 2 + qr) * 4 + t) * 1024 + lane * 16));
    c.ncil = negf(*(const short8v*)(cw + ((size_t)(3 * 2 + qr) * 4 + t) * 1024 + lane * 16));
    c.cdh  =      *(const short8v*)(cw + ((size_t)(4 * 2 + qr) * 4 + t) * 1024 + lane * 16);
    c.cdl  =      *(const short8v*)(cw + ((size_t)(5 * 2 + qr) * 4 + t) * 1024 + lane * 16);
    return c;
}

// ---------------- prep (byte-identical to proven rounds 6-11) ----------------
__global__ void pms_prep_k(const float* __restrict__ coef, char* __restrict__ wsb) {
    const int blk = blockIdx.x;
    const int lane = threadIdx.x;
    const int lrow = lane & 31, lhi = lane >> 5;
    if (blk < 84) {
        const int s = blk / 12, rem = blk % 12;
        const int mat = rem >> 1, qr = rem & 1;
        const int which = mat >> 1, lo = mat & 1;
        const float* Pr = coef + (size_t)((s + 1) * 2 + 0) * 4096;
        const float* Pi = coef + (size_t)((s + 1) * 2 + 1) * 4096;
        for (int t = 0; t < 4; ++t) {
            short8v o;
            #pragma unroll
            for (int j = 0; j < 8; ++j) {
                int idx = (16 * t + 8 * lhi + j) * 64 + 32 * qr + lrow;
                float v = (which == 0) ? Pr[idx] : (which == 1) ? Pi[idx] : (Pi[idx] - Pr[idx]);
                short hh = bf16h(v);
                o[j] = lo ? bf16h(v - bf16tof(hh)) : hh;
            }
            *(short8v*)(wsb + (size_t)s * KSLOT_STRIDE + mat * 8192 + qr * 4096 + t * 1024 + lane * 16) = o;
        }
    } else if (blk < 88) {
        const int id = blk - 84;
        const int lo = id >> 1, qr = id & 1;
        const float* Pr = coef + (size_t)(1 * 2 + 0) * 4096;
        const float* Pi = coef + (size_t)(1 * 2 + 1) * 4096;
        for (int t = 0; t < 4; ++t) {
            short8v o;
            #pragma unroll
            for (int j = 0; j < 8; ++j) {
                int idx = (16 * t + 8 * lhi + j) * 64 + 32 * qr + lrow;
                float v = Pr[idx] + Pi[idx];
                short hh = bf16h(v);
                o[j] = lo ? bf16h(v - bf16tof(hh)) : hh;
            }
            *(short8v*)(wsb + CS_OFF + lo * 8192 + qr * 4096 + t * 1024 + lane * 16) = o;
        }
    } else {
        const int id = blk - 88;
        const int qc = id & 1, qr = (id >> 1) & 1, slot = id >> 2;
        float* dst = (float*)(wsb + KINIT_OFF + (size_t)(((slot * 2 + qr) * 2 + qc) * 64 + lane) * 64);
        #pragma unroll
        for (int v = 0; v < 16; ++v) {
            int r = 32 * qr + (v & 3) + 8 * (v >> 2) + 4 * lhi;
            int c = 32 * qc + lrow;
            float c0r = coef[c * 64 + r];
            float c0i = coef[4096 + c * 64 + r];
            dst[v] = (slot == 0) ? c0r : (c0i - c0r);
        }
    }
}

// ---------------- main (round-8 structure; Xi frags in LDS) ----------------
__global__ __launch_bounds__(256, 2) void pms_main_k(
    const float* __restrict__ x, const char* __restrict__ wsb,
    float* __restrict__ out)
{
    extern __shared__ char smem[];
    const int tid  = threadIdx.x;
    const int lane = tid & 63;
    const int w    = tid >> 6;
    const int qr = w >> 1, qc = w & 1;
    const int lrow = lane & 31, lhi = lane >> 5;
    const size_t b = blockIdx.x;
    const float* xb = x + b * 8192;

    // ---- stage X into mats 0..3 (Xr h/l, Xi h/l); T_1 = X ----
    #pragma unroll
    for (int s = 0; s < 4; ++s) {
        int f = s * 1024 + tid * 4;          // 0..4095
        int m = f >> 6, c = f & 63;
        f32x4 vr = *(const f32x4*)(xb + f);
        f32x4 vi = *(const f32x4*)(xb + 4096 + f);
        HL r01 = split2(vr[0], vr[1]), r23 = split2(vr[2], vr[3]);
        HL i01 = split2(vi[0], vi[1]), i23 = split2(vi[2], vi[3]);
        int off = (m * LSTRIDE + c) * 2;
        uint2v u;
        u[0] = r01.h; u[1] = r23.h; *(uint2v*)(smem + 0 * MATB + off) = u;
        u[0] = r01.l; u[1] = r23.l; *(uint2v*)(smem + 1 * MATB + off) = u;
        u[0] = i01.h; u[1] = i23.h; *(uint2v*)(smem + 2 * MATB + off) = u;
        u[0] = i01.l; u[1] = i23.l; *(uint2v*)(smem + 3 * MATB + off) = u;
    }
    __syncthreads();

    // ---- Xr^T A-frags in registers (32 regs) ----
    short8v xr[2][4];   // [h/l][t]
    #pragma unroll
    for (int hl = 0; hl < 2; ++hl)
    #pragma unroll
    for (int t = 0; t < 4; ++t) {
        const short* mp = (const short*)(smem + hl * MATB);
        short8v a;
        #pragma unroll
        for (int j = 0; j < 8; ++j)
            a[j] = mp[(16 * t + 8 * lhi + j) * LSTRIDE + 32 * qr + lrow];
        xr[hl][t] = a;
    }

    // ---- Xi^T A-frags -> LDS frag region (16 slots, 4 per wave; round-10 scheme) ----
    #pragma unroll
    for (int i = 0; i < 4; ++i) {
        int s = w * 4 + i;                  // 0..15
        int hl = s >> 3, fqr = (s >> 2) & 1, ft = s & 3;
        const short* mp = (const short*)(smem + (2 + hl) * MATB);
        short8v a;
        #pragma unroll
        for (int j = 0; j < 8; ++j)
            a[j] = mp[(16 * ft + 8 * lhi + j) * LSTRIDE + 32 * fqr + lrow];
        *(short8v*)(smem + FRAG2OFF + ((size_t)(hl * 2 + fqr) * 4 + ft) * 1024 + lane * 16) = a;
    }

    // ---- accumulators: accRr init C0r; accQ init 0 ----
    f32x16 accRr, accQ;
    {
        const f32x4* p0 = (const f32x4*)(wsb + KINIT_OFF + (size_t)(((0 + qr) * 2 + qc) * 64 + lane) * 64);
        #pragma unroll
        for (int g = 0; g < 4; ++g) {
            f32x4 a = p0[g];
            #pragma unroll
            for (int j = 0; j < 4; ++j) { accRr[4 * g + j] = a[j]; accQ[4 * g + j] = 0.f; }
        }
    }
    __syncthreads();   // Xi frag region visible

    auto ldB = [&](int mat, int t) -> short8v {
        const short4v* p = (const short4v*)(smem + mat * MATB
                             + (32 * qc + lrow) * (LSTRIDE * 2) + 32 * t + 16 * lhi);
        short4v a = p[0], c4 = p[1];
        short8v r;
        #pragma unroll
        for (int j = 0; j < 4; ++j) { r[j] = a[j]; r[j + 4] = c4[j]; }
        return r;
    };
    auto ldXI = [&](int hl, int t) -> short8v {
        return *(const short8v*)(smem + FRAG2OFF + ((size_t)(hl * 2 + qr) * 4 + t) * 1024 + lane * 16);
    };

    // fold aTr/aTi -> T_k (6 mats incl Ts = aTr+aTi, in place, between barriers)
    auto foldWrite = [&](const f32x16& aTr, const f32x16& aTi) {
        const int c = 32 * qc + lrow;
        #pragma unroll
        for (int g = 0; g < 4; ++g) {
            int rbse = 32 * qr + 8 * g + 4 * lhi;
            int off = (c * LSTRIDE + rbse) * 2;
            float s0 = aTr[4 * g + 0] + aTi[4 * g + 0];
            float s1 = aTr[4 * g + 1] + aTi[4 * g + 1];
            float s2 = aTr[4 * g + 2] + aTi[4 * g + 2];
            float s3 = aTr[4 * g + 3] + aTi[4 * g + 3];
            HL a01 = split2(aTr[4 * g + 0], aTr[4 * g + 1]);
            HL a23 = split2(aTr[4 * g + 2], aTr[4 * g + 3]);
            HL b01 = split2(aTi[4 * g + 0], aTi[4 * g + 1]);
            HL b23 = split2(aTi[4 * g + 2], aTi[4 * g + 3]);
            HL c01 = split2(s0, s1);
            HL c23 = split2(s2, s3);
            uint2v u;
            u[0] = a01.h; u[1] = a23.h; *(uint2v*)(smem + 0 * MATB + off) = u;
            u[0] = a01.l; u[1] = a23.l; *(uint2v*)(smem + 1 * MATB + off) = u;
            u[0] = b01.h; u[1] = b23.h; *(uint2v*)(smem + 2 * MATB + off) = u;
            u[0] = b01.l; u[1] = b23.l; *(uint2v*)(smem + 3 * MATB + off) = u;
            u[0] = c01.h; u[1] = c23.h; *(uint2v*)(smem + 4 * MATB + off) = u;
            u[0] = c01.l; u[1] = c23.l; *(uint2v*)(smem + 5 * MATB + off) = u;
        }
    };

    CF cnxt;   // next-kslot t=0 prefetch

    // ---- peeled k=2: apply C1 (quirk: accQ += Cd*Tr + Cs*Ti) + chain T2 = X*X ----
    {
        const char* cw = wsb;   // kslot 0
        f32x16 aTr, aTi;
        #pragma unroll
        for (int j = 0; j < 16; ++j) { aTr[j] = 0.f; aTi[j] = 0.f; }
        CF c0 = loadCF(cw, qr, lane, 0);
        short8v Brh = ldB(0, 0), Brl = ldB(1, 0);
        short8v Bih = ldB(2, 0), Bil = ldB(3, 0);
        #pragma unroll
        for (int t = 0; t < 4; ++t) {
            CF c1; short8v Nrh, Nrl, Nih, Nil;
            if (t < 3) {
                c1 = loadCF(cw, qr, lane, t + 1);
                Nrh = ldB(0, t + 1); Nrl = ldB(1, t + 1);
                Nih = ldB(2, t + 1); Nil = ldB(3, t + 1);
            }
            short8v csh = *(const short8v*)(wsb + CS_OFF + ((size_t)(0 * 2 + qr) * 4 + t) * 1024 + lane * 16);
            short8v csl = *(const short8v*)(wsb + CS_OFF + ((size_t)(1 * 2 + qr) * 4 + t) * 1024 + lane * 16);
            short8v Xih = ldXI(0, t), Xil = ldXI(1, t);
            short8v nBih = negf(Bih), nBil = negf(Bil);

            __builtin_amdgcn_s_setprio(1);
            accRr = MF(c0.crh, Brh, accRr);
            aTr   = MF(xr[0][t], Brh, aTr);
            aTi   = MF(Xih, Brh, aTi);
            accQ  = MF(c0.cdh, Brh, accQ);

            accRr = MF(c0.crh, Brl, accRr);
            aTr   = MF(xr[0][t], Brl, aTr);
            aTi   = MF(Xih, Brl, aTi);
            accQ  = MF(c0.cdh, Brl, accQ);

            accRr = MF(c0.crl, Brh, accRr);
            aTr   = MF(xr[1][t], Brh, aTr);
            aTi   = MF(Xil, Brh, aTi);
            accQ  = MF(c0.cdl, Brh, accQ);

            accRr = MF(c0.ncih, Bih, accRr);
            aTr   = MF(Xih, nBih, aTr);
            aTi   = MF(xr[0][t], Bih, aTi);
            accQ  = MF(csh, Bih, accQ);

            accRr = MF(c0.ncih, Bil, accRr);
            aTr   = MF(Xih, nBil, aTr);
            aTi   = MF(xr[0][t], Bil, aTi);
            accQ  = MF(csh, Bil, accQ);

            accRr = MF(c0.ncil, Bih, accRr);
            aTr   = MF(Xil, nBih, aTr);
            aTi   = MF(xr[1][t], Bih, aTi);
            accQ  = MF(csl, Bih, accQ);
            __builtin_amdgcn_s_setprio(0);

            if (t < 3) { c0 = c1; Brh = Nrh; Brl = Nrl; Bih = Nih; Bil = Nil; }
        }
        cnxt = loadCF(wsb + (size_t)1 * KSLOT_STRIDE, qr, lane, 0);
        __syncthreads();
        foldWrite(aTr, aTi);
        __syncthreads();
    }

    // ---- k=3..7 (ks=1..5): coeff 9/t (accQ += Cd*Ts) + chain 12/t ----
    for (int ks = 1; ks <= 5; ++ks) {
        const char* cw = wsb + (size_t)ks * KSLOT_STRIDE;
        f32x16 aTr, aTi;
        #pragma unroll
        for (int j = 0; j < 16; ++j) { aTr[j] = 0.f; aTi[j] = 0.f; }
        CF c0 = cnxt;
        short8v Brh = ldB(0, 0), Brl = ldB(1, 0);
        short8v Bih = ldB(2, 0), Bil = ldB(3, 0);
        #pragma unroll
        for (int t = 0; t < 4; ++t) {
            CF c1; short8v Nrh, Nrl, Nih, Nil;
            if (t < 3) {
                c1 = loadCF(cw, qr, lane, t + 1);
                Nrh = ldB(0, t + 1); Nrl = ldB(1, t + 1);
                Nih = ldB(2, t + 1); Nil = ldB(3, t + 1);
            }
            short8v Bsh = ldB(4, t), Bsl = ldB(5, t);   // JIT; consumed late
            short8v Xih = ldXI(0, t), Xil = ldXI(1, t);
            short8v nBih = negf(Bih), nBil = negf(Bil);

            __builtin_amdgcn_s_setprio(1);
            accRr = MF(c0.crh, Brh, accRr);
            aTr   = MF(xr[0][t], Brh, aTr);
            aTi   = MF(Xih, Brh, aTi);

            accRr = MF(c0.crh, Brl, accRr);
            aTr   = MF(xr[0][t], Brl, aTr);
            aTi   = MF(Xih, Brl, aTi);

            accRr = MF(c0.crl, Brh, accRr);
            aTr   = MF(xr[1][t], Brh, aTr);
            aTi   = MF(Xil, Brh, aTi);

            accRr = MF(c0.ncih, Bih, accRr);
            aTr   = MF(Xih, nBih, aTr);
            aTi   = MF(xr[0][t], Bih, aTi);
            accQ  = MF(c0.cdh, Bsh, accQ);

            accRr = MF(c0.ncih, Bil, accRr);
            aTr   = MF(Xih, nBil, aTr);
            aTi   = MF(xr[0][t], Bil, aTi);
            accQ  = MF(c0.cdh, Bsl, accQ);

            accRr = MF(c0.ncil, Bih, accRr);
            aTr   = MF(Xil, nBih, aTr);
            aTi   = MF(xr[1][t], Bih, aTi);
            accQ  = MF(c0.cdl, Bsh, accQ);
            __builtin_amdgcn_s_setprio(0);

            if (t < 3) { c0 = c1; Brh = Nrh; Brl = Nrl; Bih = Nih; Bil = Nil; }
        }
        cnxt = loadCF(wsb + (size_t)(ks + 1) * KSLOT_STRIDE, qr, lane, 0);  // ks=5 -> kslot 6
        __syncthreads();
        foldWrite(aTr, aTi);
        __syncthreads();
    }

    // ---- final: apply C7 (kslot 6) on T7: 9 MFMAs/t ----
    {
        CF c0 = cnxt;
        const char* cw = wsb + (size_t)6 * KSLOT_STRIDE;
        short8v Brh = ldB(0, 0), Brl = ldB(1, 0);
        short8v Bih = ldB(2, 0), Bil = ldB(3, 0);
        #pragma unroll
        for (int t = 0; t < 4; ++t) {
            CF c1; short8v Nrh, Nrl, Nih, Nil;
            if (t < 3) {
                c1 = loadCF(cw, qr, lane, t + 1);
                Nrh = ldB(0, t + 1); Nrl = ldB(1, t + 1);
                Nih = ldB(2, t + 1); Nil = ldB(3, t + 1);
            }
            short8v Bsh = ldB(4, t), Bsl = ldB(5, t);

            __builtin_amdgcn_s_setprio(1);
            accRr = MF(c0.crh, Brh, accRr);
            accQ  = MF(c0.cdh, Bsh, accQ);
            accRr = MF(c0.crh, Brl, accRr);
            accQ  = MF(c0.cdh, Bsl, accQ);
            accRr = MF(c0.crl, Brh, accRr);
            accQ  = MF(c0.cdl, Bsh, accQ);
            accRr = MF(c0.ncih, Bih, accRr);
            accRr = MF(c0.ncih, Bil, accRr);
            accRr = MF(c0.ncil, Bih, accRr);
            __builtin_amdgcn_s_setprio(0);

            if (t < 3) { c0 = c1; Brh = Nrh; Brl = Nrl; Bih = Nih; Bil = Nil; }
        }
    }

    // ---- epilogue: res_r = accRr; res_i = accRr + accQ + (C0i - C0r) ----
    f32x16 accRi;
    {
        const f32x4* p1 = (const f32x4*)(wsb + KINIT_OFF + (size_t)(((2 + qr) * 2 + qc) * 64 + lane) * 64);
        #pragma unroll
        for (int g = 0; g < 4; ++g) {
            f32x4 d = p1[g];
            #pragma unroll
            for (int j = 0; j < 4; ++j)
                accRi[4 * g + j] = accRr[4 * g + j] + accQ[4 * g + j] + d[j];
        }
    }
    __syncthreads();   // done reading T region; reuse for f32 transpose staging
    {
        const int c = 32 * qc + lrow;
        #pragma unroll
        for (int g = 0; g < 4; ++g) {
            int rbse = 32 * qr + 8 * g + 4 * lhi;
            f32x4 vr, vi;
            #pragma unroll
            for (int j = 0; j < 4; ++j) { vr[j] = accRr[4 * g + j]; vi[j] = accRi[4 * g + j]; }
            *(f32x4*)(smem + (size_t)(0 * 4352 + c * LSTRIDE + rbse) * 4) = vr;
            *(f32x4*)(smem + (size_t)(1 * 4352 + c * LSTRIDE + rbse) * 4) = vi;
        }
    }
    __syncthreads();
    float* ob = out + b * 8192;
    #pragma unroll
    for (int s = 0; s < 8; ++s) {
        int f = s * 1024 + tid * 4;
        int p = f >> 12, m = (f >> 6) & 63, n = f & 63;
        *(f32x4*)(ob + f) = *(const f32x4*)(smem + (size_t)(p * 4352 + m * LSTRIDE + n) * 4);
    }
}

extern "C" void kernel_launch(void* const* d_in, const int* in_sizes, int n_in,
                              void* d_out, int out_size, void* d_ws, size_t ws_size,
                              hipStream_t stream) {
    const float* x    = (const float*)d_in[0];
    const float* coef = (const float*)d_in[1];
    float* out = (float*)d_out;
    char*  wsb = (char*)d_ws;
    const int B = in_sizes[0] / 8192;   // 2048

    (void)hipFuncSetAttribute(reinterpret_cast<const void*>(&pms_main_k),
                              hipFuncAttributeMaxDynamicSharedMemorySize, LDSZ);

    pms_prep_k<<<96, 64, 0, stream>>>(coef, wsb);
    pms_main_k<<<B, 256, LDSZ, stream>>>(x, wsb, out);
}

// Round 13
// 144.544 us; speedup vs baseline: 1.6114x; 1.0516x over previous
//
#include <hip/hip_runtime.h>

typedef __attribute__((ext_vector_type(4))) short short4v;
typedef __attribute__((ext_vector_type(8))) short short8v;
typedef __attribute__((ext_vector_type(2))) unsigned int uint2v;
typedef __attribute__((ext_vector_type(4))) unsigned int uint4v;
typedef __attribute__((ext_vector_type(4))) float f32x4;
typedef __attribute__((ext_vector_type(16))) float f32x16;

#define LSTRIDE 68                 // bf16 elems per LDS row (136 B; stride/8 odd -> conflict-free b64)
#define MATB (64 * LSTRIDE * 2)    // 8704 B per 64x64 bf16 matrix
#define REGA 0
#define REGB (4 * MATB)            // ping-pong region
#define LDS_BYTES (8 * MATB)       // 69632 -> 2 WG/CU

// ws: [kslot 0..6][mat 0..3][qr][t][lane*16B]; mat: 0=Cr_h 1=Cr_l 2=Ci_h 3=Ci_l
#define CFRAG_BYTES (7 * 4 * 2 * 4 * 1024)  // 229376
#define INIT_OFF CFRAG_BYTES                // + 32768: [part][qr][qc][lane][16 f32]

__device__ __forceinline__ short bf16h(float v) {
    union { float f; unsigned u; } x; x.f = v;
    unsigned r = x.u + 0x7FFFu + ((x.u >> 16) & 1u);
    return (short)(r >> 16);
}
__device__ __forceinline__ float bf16tof(short s) {
    union { unsigned u; float f; } x; x.u = ((unsigned)(unsigned short)s) << 16;
    return x.f;
}
// split two f32 into packed-bf16 high parts and packed-bf16 low (residual) parts
struct HL { unsigned h, l; };
__device__ __forceinline__ HL split2(float v0, float v1) {
    unsigned hp, lp;
    asm("v_cvt_pk_bf16_f32 %0, %1, %2" : "=v"(hp) : "v"(v0), "v"(v1));
    union { unsigned u; float f; } a, b;
    a.u = hp << 16;            // float of bf16(v0)
    b.u = hp & 0xffff0000u;    // float of bf16(v1)
    float l0 = v0 - a.f, l1 = v1 - b.f;
    asm("v_cvt_pk_bf16_f32 %0, %1, %2" : "=v"(lp) : "v"(l0), "v"(l1));
    HL r; r.h = hp; r.l = lp; return r;
}
__device__ __forceinline__ f32x16 MF(short8v a, short8v b, f32x16 c) {
    return __builtin_amdgcn_mfma_f32_32x32x16_bf16(a, b, c, 0, 0, 0);
}
__device__ __forceinline__ short8v negf(short8v a) {   // negate 8 bf16 (packed xor)
    uint4v u = __builtin_bit_cast(uint4v, a);
    u ^= 0x80008000u;
    return __builtin_bit_cast(short8v, u);
}

// ---------------- prep: coefficients -> ws ----------------
__global__ void pms_prep(const float* __restrict__ coef, char* __restrict__ wsb) {
    const int blk = blockIdx.x;
    const int lane = threadIdx.x;
    const int lrow = lane & 31, lhi = lane >> 5;
    if (blk < 56) {
        const int qr  = blk & 1;
        const int km  = blk >> 1;
        const int mat = km & 3;
        const int kk  = km >> 2;            // kslot 0..6 <-> coefficient index kk+1
        const int part = mat >> 1;
        const int lo   = mat & 1;
        const float* C = coef + (size_t)((kk + 1) * 2 + part) * 4096;
        for (int t = 0; t < 4; ++t) {
            short8v o;
            #pragma unroll
            for (int j = 0; j < 8; ++j) {
                int krow = 16 * t + 8 * lhi + j;
                int col  = 32 * qr + lrow;
                float v = C[krow * 64 + col];           // C^T[col][krow]
                short hh = bf16h(v);
                o[j] = lo ? bf16h(v - bf16tof(hh)) : hh;
            }
            *(short8v*)(wsb + ((size_t)blk * 4 + t) * 1024 + lane * 16) = o;
        }
    } else {
        const int id = blk - 56;            // [part][qr][qc]
        const int qc = id & 1, qr = (id >> 1) & 1, part = id >> 2;
        const float* C0 = coef + (size_t)part * 4096;
        float* dst = (float*)(wsb + INIT_OFF + (size_t)(((part * 2 + qr) * 2 + qc) * 64 + lane) * 64);
        #pragma unroll
        for (int v = 0; v < 16; ++v) {
            int r = 32 * qr + (v & 3) + 8 * (v >> 2) + 4 * lhi;  // D-layout row
            int c = 32 * qc + lrow;                               // D-layout col
            dst[v] = C0[c * 64 + r];        // C0^T[r][c]
        }
    }
}

// ---------------- main ----------------
__global__ __launch_bounds__(256, 2) void pms_main(
    const float* __restrict__ x, const char* __restrict__ wsb,
    float* __restrict__ out)
{
    extern __shared__ char smem[];
    const int tid  = threadIdx.x;
    const int lane = tid & 63;
    const int w    = tid >> 6;
    const int qr = w >> 1, qc = w & 1;
    const int lrow = lane & 31, lhi = lane >> 5;
    const size_t b = blockIdx.x;
    const float* xb = x + b * 8192;

    // ---- stage X (row-major) as split bf16 into REGA; doubles as T_1 ----
    #pragma unroll
    for (int s = 0; s < 8; ++s) {
        int f = s * 1024 + tid * 4;
        int p = f >> 12, m = (f >> 6) & 63, c = f & 63;
        f32x4 v = *(const f32x4*)(xb + f);
        HL a01 = split2(v[0], v[1]);
        HL a23 = split2(v[2], v[3]);
        uint2v h, l;
        h[0] = a01.h; l[0] = a01.l;
        h[1] = a23.h; l[1] = a23.l;
        int off = (m * LSTRIDE + c) * 2;
        *(uint2v*)(smem + REGA + (p * 2 + 0) * MATB + off) = h;
        *(uint2v*)(smem + REGA + (p * 2 + 1) * MATB + off) = l;
    }
    __syncthreads();

    // ---- one-time A-fragments of X^T (registers, all iterations) ----
    short8v xa[2][2][4];   // [r/i][h/l][ktile]
    #pragma unroll
    for (int pi = 0; pi < 2; ++pi)
    #pragma unroll
    for (int hl = 0; hl < 2; ++hl)
    #pragma unroll
    for (int t = 0; t < 4; ++t) {
        const short* mp = (const short*)(smem + REGA + (pi * 2 + hl) * MATB);
        short8v a;
        #pragma unroll
        for (int j = 0; j < 8; ++j)
            a[j] = mp[(16 * t + 8 * lhi + j) * LSTRIDE + 32 * qr + lrow];  // X^T[r][k]
        xa[pi][hl][t] = a;
    }

    // ---- accumulators init = C0^T fragments ----
    f32x16 accRr, accRi;
    {
        const f32x4* p0 = (const f32x4*)(wsb + INIT_OFF + (size_t)(((0 + qr) * 2 + qc) * 64 + lane) * 64);
        const f32x4* p1 = (const f32x4*)(wsb + INIT_OFF + (size_t)(((2 + qr) * 2 + qc) * 64 + lane) * 64);
        #pragma unroll
        for (int g = 0; g < 4; ++g) {
            f32x4 a = p0[g], c4 = p1[g];
            #pragma unroll
            for (int j = 0; j < 4; ++j) { accRr[4 * g + j] = a[j]; accRi[4 * g + j] = c4[j]; }
        }
    }

    // B-fragment: lane reads lds_T[n = 32qc+lrow][k = 16t+8lhi .. +7], two b64s
    auto ldB = [&](int rbase, int mat, int t) -> short8v {
        const short4v* p = (const short4v*)(smem + rbase + mat * MATB
                             + (32 * qc + lrow) * (LSTRIDE * 2) + 32 * t + 16 * lhi);
        short4v a = p[0], c4 = p[1];
        short8v r;
        #pragma unroll
        for (int j = 0; j < 4; ++j) { r[j] = a[j]; r[j + 4] = c4[j]; }
        return r;
    };

    int cur = REGA, nxt = REGB;

    // ---- fused loop: iteration k applies C_{k-1} to T_{k-1} AND computes T_k -> nxt ----
    for (int k = 2; k <= 7; ++k) {
        const char* cw = wsb + (size_t)(k - 2) * 32768;   // kslot k-2
        const bool k1 = (k == 2);

        // prefetch ALL 16 coefficient A-frags for this iteration (global, L2-resident)
        short8v cRh[4], cRl[4], cIh[4], cIl[4];
        #pragma unroll
        for (int t = 0; t < 4; ++t) {
            cRh[t] = *(const short8v*)(cw + ((0 * 2 + qr) * 4 + t) * 1024 + lane * 16);
            cRl[t] = *(const short8v*)(cw + ((1 * 2 + qr) * 4 + t) * 1024 + lane * 16);
            cIh[t] = *(const short8v*)(cw + ((2 * 2 + qr) * 4 + t) * 1024 + lane * 16);
            cIl[t] = *(const short8v*)(cw + ((3 * 2 + qr) * 4 + t) * 1024 + lane * 16);
        }
        // B prefetch t=0
        short8v Brh = ldB(cur, 0, 0), Brl = ldB(cur, 1, 0);
        short8v Bih = ldB(cur, 2, 0), Bil = ldB(cur, 3, 0);

        f32x16 aTr, aTi;
        #pragma unroll
        for (int v = 0; v < 16; ++v) { aTr[v] = 0.f; aTi[v] = 0.f; }

        #pragma unroll
        for (int t = 0; t < 4; ++t) {
            // issue next t's B-frag reads before this t's MFMA cluster
            short8v Nrh, Nrl, Nih, Nil;
            if (t < 3) {
                Nrh = ldB(cur, 0, t + 1); Nrl = ldB(cur, 1, t + 1);
                Nih = ldB(cur, 2, t + 1); Nil = ldB(cur, 3, t + 1);
            }
            short8v nBih = negf(Bih), nBil = negf(Bil);        // -Ti
            short8v sBih = k1 ? Bih : nBih;                    // sign quirk: +Cr*Ti at k=1 only
            short8v sBil = k1 ? Bil : nBil;

            __builtin_amdgcn_s_setprio(1);
            // 24 MFMAs, 4 independent chains round-robin
            accRr = MF(cRh[t], Brh, accRr);
            accRi = MF(cIh[t], Brh, accRi);
            aTr   = MF(xa[0][0][t], Brh, aTr);
            aTi   = MF(xa[1][0][t], Brh, aTi);

            accRr = MF(cRh[t], Brl, accRr);
            accRi = MF(cIh[t], Brl, accRi);
            aTr   = MF(xa[0][0][t], Brl, aTr);
            aTi   = MF(xa[1][0][t], Brl, aTi);

            accRr = MF(cRl[t], Brh, accRr);
            accRi = MF(cIl[t], Brh, accRi);
            aTr   = MF(xa[0][1][t], Brh, aTr);
            aTi   = MF(xa[1][1][t], Brh, aTi);

            accRr = MF(cIh[t], nBih, accRr);      // -Ci*Ti
            accRi = MF(cRh[t], sBih, accRi);      // ±Cr*Ti
            aTr   = MF(xa[1][0][t], nBih, aTr);   // -Xi*Ti
            aTi   = MF(xa[0][0][t], Bih, aTi);    // +Xr*Ti

            accRr = MF(cIh[t], nBil, accRr);
            accRi = MF(cRh[t], sBil, accRi);
            aTr   = MF(xa[1][0][t], nBil, aTr);
            aTi   = MF(xa[0][0][t], Bil, aTi);

            accRr = MF(cIl[t], nBih, accRr);
            accRi = MF(cRl[t], sBih, accRi);
            aTr   = MF(xa[1][1][t], nBih, aTr);
            aTi   = MF(xa[0][1][t], Bih, aTi);
            __builtin_amdgcn_s_setprio(0);

            if (t < 3) { Brh = Nrh; Brl = Nrl; Bih = Nih; Bil = Nil; }
        }

        // split aTr/aTi (cvt_pk) and write T_k into nxt (no barrier needed before: nxt != cur)
        {
            const int c = 32 * qc + lrow;
            #pragma unroll
            for (int g = 0; g < 4; ++g) {
                int rbse = 32 * qr + 8 * g + 4 * lhi;
                HL r01 = split2(aTr[4 * g + 0], aTr[4 * g + 1]);
                HL r23 = split2(aTr[4 * g + 2], aTr[4 * g + 3]);
                HL i01 = split2(aTi[4 * g + 0], aTi[4 * g + 1]);
                HL i23 = split2(aTi[4 * g + 2], aTi[4 * g + 3]);
                uint2v hr, lr, hi2, li2;
                hr[0] = r01.h; lr[0] = r01.l; hr[1] = r23.h; lr[1] = r23.l;
                hi2[0] = i01.h; li2[0] = i01.l; hi2[1] = i23.h; li2[1] = i23.l;
                int off = (c * LSTRIDE + rbse) * 2;
                *(uint2v*)(smem + nxt + 0 * MATB + off) = hr;
                *(uint2v*)(smem + nxt + 1 * MATB + off) = lr;
                *(uint2v*)(smem + nxt + 2 * MATB + off) = hi2;
                *(uint2v*)(smem + nxt + 3 * MATB + off) = li2;
            }
        }
        __syncthreads();   // T_k visible; also guarantees everyone done reading cur
        int tmp = cur; cur = nxt; nxt = tmp;
    }

    // ---- final coefficient term: C_7 (kslot 6) on T_7 (in cur) ----
    {
        const char* cw = wsb + (size_t)6 * 32768;
        short8v cRh[4], cRl[4], cIh[4], cIl[4];
        #pragma unroll
        for (int t = 0; t < 4; ++t) {
            cRh[t] = *(const short8v*)(cw + ((0 * 2 + qr) * 4 + t) * 1024 + lane * 16);
            cRl[t] = *(const short8v*)(cw + ((1 * 2 + qr) * 4 + t) * 1024 + lane * 16);
            cIh[t] = *(const short8v*)(cw + ((2 * 2 + qr) * 4 + t) * 1024 + lane * 16);
            cIl[t] = *(const short8v*)(cw + ((3 * 2 + qr) * 4 + t) * 1024 + lane * 16);
        }
        short8v Brh = ldB(cur, 0, 0), Brl = ldB(cur, 1, 0);
        short8v Bih = ldB(cur, 2, 0), Bil = ldB(cur, 3, 0);
        #pragma unroll
        for (int t = 0; t < 4; ++t) {
            short8v Nrh, Nrl, Nih, Nil;
            if (t < 3) {
                Nrh = ldB(cur, 0, t + 1); Nrl = ldB(cur, 1, t + 1);
                Nih = ldB(cur, 2, t + 1); Nil = ldB(cur, 3, t + 1);
            }
            short8v nBih = negf(Bih), nBil = negf(Bil);

            __builtin_amdgcn_s_setprio(1);
            accRr = MF(cRh[t], Brh, accRr);
            accRi = MF(cIh[t], Brh, accRi);
            accRr = MF(cRh[t], Brl, accRr);
            accRi = MF(cIh[t], Brl, accRi);
            accRr = MF(cRl[t], Brh, accRr);
            accRi = MF(cIl[t], Brh, accRi);
            accRr = MF(cIh[t], nBih, accRr);
            accRi = MF(cRh[t], nBih, accRi);
            accRr = MF(cIh[t], nBil, accRr);
            accRi = MF(cRh[t], nBil, accRi);
            accRr = MF(cIl[t], nBih, accRr);
            accRi = MF(cRl[t], nBih, accRi);
            __builtin_amdgcn_s_setprio(0);

            if (t < 3) { Brh = Nrh; Brl = Nrl; Bih = Nih; Bil = Nil; }
        }
    }

    __syncthreads();   // done reading cur; nxt region is dead -> f32 transpose staging
    {
        const int c = 32 * qc + lrow;
        #pragma unroll
        for (int g = 0; g < 4; ++g) {
            int rbse = 32 * qr + 8 * g + 4 * lhi;
            f32x4 vr, vi;
            #pragma unroll
            for (int j = 0; j < 4; ++j) { vr[j] = accRr[4 * g + j]; vi[j] = accRi[4 * g + j]; }
            *(f32x4*)(smem + nxt + (size_t)(0 * 4352 + c * LSTRIDE + rbse) * 4) = vr;
            *(f32x4*)(smem + nxt + (size_t)(1 * 4352 + c * LSTRIDE + rbse) * 4) = vi;
        }
    }
    __syncthreads();
    float* ob = out + b * 8192;
    #pragma unroll
    for (int s = 0; s < 8; ++s) {
        int f = s * 1024 + tid * 4;
        int p = f >> 12, m = (f >> 6) & 63, n = f & 63;
        *(f32x4*)(ob + f) = *(const f32x4*)(smem + nxt + (size_t)(p * 4352 + m * LSTRIDE + n) * 4);
    }
}

extern "C" void kernel_launch(void* const* d_in, const int* in_sizes, int n_in,
                              void* d_out, int out_size, void* d_ws, size_t ws_size,
                              hipStream_t stream) {
    const float* x    = (const float*)d_in[0];
    const float* coef = (const float*)d_in[1];
    float* out = (float*)d_out;
    char*  wsb = (char*)d_ws;
    const int B = in_sizes[0] / 8192;   // 2048

    (void)hipFuncSetAttribute(reinterpret_cast<const void*>(&pms_main),
                              hipFuncAttributeMaxDynamicSharedMemorySize, LDS_BYTES);

    pms_prep<<<64, 64, 0, stream>>>(coef, wsb);
    pms_main<<<B, 256, LDS_BYTES, stream>>>(x, wsb, out);
}